// Round 7
// baseline (833.622 us; speedup 1.0000x reference)
//
#include <hip/hip_runtime.h>
#include <cmath>

#define NTOK 32768   // 8*4096 tokens
#define EMB  2048
#define NEXP 64
#define TOPK 8
#define BT   64      // tokens per block (4 waves x 16 tokens)
#define KC   16      // K-chunk per prefetch stage (one 64B line per row)
#define NCH  (EMB / KC)   // 128

typedef __attribute__((ext_vector_type(4))) double d4;

__global__ __launch_bounds__(256, 4) void router_mfma(
    const float* __restrict__ X,   // [NTOK][EMB]
    const float* __restrict__ W,   // [NEXP][EMB]
    const float* __restrict__ Bv,  // [NEXP]
    float* __restrict__ out)       // probs [NTOK][64] fp32, then indices [NTOK][8] as fp32
{
    // No LDS, no barriers. Each wave owns 16 tokens x 64 experts and
    // register-prefetches its MFMA fragments straight from global:
    //   A: lane(eL,q) needs X[tok=eL][k=4s+q]  -> 16B segments, 64B line / chunk
    //   B: lane(eL,q) needs W[c*16+eL][k=4s+q] -> W chunk stays L1/L2-hot
    const int tid  = threadIdx.x;
    const int lane = tid & 63;
    const int wv   = tid >> 6;        // token tile: tokens wv*16 .. wv*16+15
    const int t0   = blockIdx.x * BT;
    const int eL   = lane & 15;       // A: token row; B: expert col
    const int q    = lane >> 4;       // fragment k offset

    const float* xr = X + (size_t)(t0 + wv * 16 + eL) * EMB + q;
    const float* wr[4];
    #pragma unroll
    for (int c = 0; c < 4; ++c) wr[c] = W + (size_t)(c * 16 + eL) * EMB + q;

    // acc[c] = D tile for experts c*16..c*16+15; init with bias (col-constant)
    d4 acc[4];
    #pragma unroll
    for (int c = 0; c < 4; ++c) {
        const double b = (double)Bv[c * 16 + eL];
        acc[c] = (d4){b, b, b, b};
    }

    // ping-pong staging registers: 20 f32 per chunk
    float a0[4], a1[4], b0[16], b1[16];

#define LOADC(ch, A, B)                                        \
    {                                                          \
        const int kc = (ch) * KC;                              \
        _Pragma("unroll")                                      \
        for (int s = 0; s < 4; ++s) {                          \
            A[s] = xr[kc + 4 * s];                             \
            _Pragma("unroll")                                  \
            for (int c = 0; c < 4; ++c)                        \
                B[c * 4 + s] = wr[c][kc + 4 * s];              \
        }                                                      \
    }

#define COMPUTE(A, B)                                          \
    {                                                          \
        _Pragma("unroll")                                      \
        for (int s = 0; s < 4; ++s) {                          \
            const double aF = (double)A[s];                    \
            _Pragma("unroll")                                  \
            for (int c = 0; c < 4; ++c)                        \
                acc[c] = __builtin_amdgcn_mfma_f64_16x16x4f64( \
                    aF, (double)B[c * 4 + s], acc[c], 0, 0, 0);\
        }                                                      \
    }

    LOADC(0, a0, b0);
    LOADC(1, a1, b1);
    for (int ch = 0; ch < NCH; ch += 2) {
        COMPUTE(a0, b0);                       // waits (fine-grained vmcnt) on chunk ch
        if (ch + 2 < NCH) LOADC(ch + 2, a0, b0);
        COMPUTE(a1, b1);
        if (ch + 3 < NCH) LOADC(ch + 3, a1, b1);
    }
#undef LOADC
#undef COMPUTE

    // ---- epilogue: top-8 + masked softmax, fully in registers/shfl ----
    // f64 MFMA D layout: token row = (lane>>4) + 4*reg, expert col = c*16 + (lane&15)
    float* probs = out;                        // [NTOK][64]
    float* idxo  = out + (size_t)NTOK * NEXP;  // [NTOK][8] index values as f32

    #pragma unroll
    for (int i = 0; i < 4; ++i) {
        const int T = t0 + wv * 16 + q + 4 * i;
        double v[4];
        #pragma unroll
        for (int c = 0; c < 4; ++c) v[c] = acc[c][i];

        unsigned sel = 0;
        double m0 = 0.0;
        float ssum = 0.0f;
        int myIdx = 0;
        #pragma unroll
        for (int it = 0; it < TOPK; ++it) {
            // local best among unselected candidates (c ascending => lowest index on tie)
            double bv = -1.0e300;
            int    be = 1 << 30;
            #pragma unroll
            for (int c = 0; c < 4; ++c)
                if (!((sel >> c) & 1) && v[c] > bv) { bv = v[c]; be = c * 16 + eL; }
            // 16-lane group argmax (xor 1,2,4,8 stays inside the group)
            double gv = bv; int ge = be;
            #pragma unroll
            for (int off = 1; off <= 8; off <<= 1) {
                const double ov = __shfl_xor(gv, off, 64);
                const int    oe = __shfl_xor(ge, off, 64);
                if (ov > gv || (ov == gv && oe < ge)) { gv = ov; ge = oe; }
            }
            if (it == 0) m0 = gv;
            ssum += __expf((float)(gv - m0));
            if ((ge & 15) == eL) sel |= 1u << (ge >> 4);  // owner lane marks candidate
            if (eL == it) myIdx = ge;                     // lane 'it' records rank-it index
        }
        const float inv = 1.0f / ssum;
        #pragma unroll
        for (int c = 0; c < 4; ++c) {
            const float p = ((sel >> c) & 1) ? __expf((float)(v[c] - m0)) * inv : 0.0f;
            probs[(size_t)T * NEXP + c * 16 + eL] = p;
        }
        if (eL < TOPK) idxo[(size_t)T * TOPK + eL] = (float)myIdx;
    }
}

extern "C" void kernel_launch(void* const* d_in, const int* in_sizes, int n_in,
                              void* d_out, int out_size, void* d_ws, size_t ws_size,
                              hipStream_t stream) {
    const float* X = (const float*)d_in[0];
    const float* W = (const float*)d_in[1];
    const float* B = (const float*)d_in[2];
    router_mfma<<<NTOK / BT, 256, 0, stream>>>(X, W, B, (float*)d_out);
}

// Round 8
// 459.090 us; speedup vs baseline: 1.8158x; 1.8158x over previous
//
#include <hip/hip_runtime.h>
#include <cmath>

#define NTOK 32768
#define EMB  2048
#define NEXP 64
#define TOPK 8
#define BT   64
#define KC   32
#define NCH  (EMB / KC)
#define DELTA 1e-4f
#define WL_CAP 32768
#define WOFF  (256*1024)      // byte offset of bf16 W planes in ws
#define PLANE (NEXP*EMB)      // elements per plane

typedef __attribute__((ext_vector_type(8))) short bf8;
typedef __attribute__((ext_vector_type(4))) float f4;

__device__ __forceinline__ unsigned short bf16rn(float x){
    union{float f; unsigned u;} c; c.f = x;
    return (unsigned short)((c.u + 0x7FFFu + ((c.u >> 16) & 1u)) >> 16);
}
__device__ __forceinline__ float bf2f(unsigned short b){
    union{unsigned u; float f;} c; c.u = ((unsigned)b) << 16; return c.f;
}
__device__ __forceinline__ void gld16(const void* g, void* lds){
    __builtin_amdgcn_global_load_lds(
        (const __attribute__((address_space(1))) void*)g,
        (__attribute__((address_space(3))) void*)lds, 16, 0, 0);
}

// ---- kernel 0: split W fp32 -> 3 exact bf16 planes in ws ----
__global__ __launch_bounds__(256) void wsplit(const float* __restrict__ W,
                                              unsigned short* __restrict__ wp){
    int i = blockIdx.x * 256 + threadIdx.x;
    #pragma unroll
    for (int rep = 0; rep < 2; ++rep, i += 65536){
        const float x = W[i];
        const unsigned short b1 = bf16rn(x);  const float r  = x - bf2f(b1);
        const unsigned short b2 = bf16rn(r);  const float r2 = r - bf2f(b2);
        const unsigned short b3 = bf16rn(r2);
        wp[i] = b1; wp[PLANE + i] = b2; wp[2*PLANE + i] = b3;
    }
}

// ---- kernel 1: bf16 6-pass MFMA GEMM + top-9 gap certification ----
__global__ __launch_bounds__(256) void router_bf16(
    const float* __restrict__ X, const unsigned short* __restrict__ WP,
    const float* __restrict__ Bv, float* __restrict__ out, int* __restrict__ wsi)
{
    __shared__ __align__(16) unsigned short xs[2][3][BT*KC];    // 24 KB
    __shared__ __align__(16) unsigned short wsh[2][3][NEXP*KC]; // 24 KB

    const int tid = threadIdx.x, lane = tid & 63, wv = tid >> 6;
    const int t0 = blockIdx.x * BT;
    const int eL = lane & 15, q = lane >> 4;

    // X staging ids: thread covers row sr, 8-elem k-group sj
    const int sr = tid >> 2, sj = tid & 3;
    const float* xg = X + (size_t)(t0 + sr)*EMB + 8*sj;
    // W gld-lds source: lane covers row rw, group (lane&3)
    const int rw = wv*16 + (lane >> 2);
    const unsigned short* wg = WP + (size_t)rw*EMB + 8*(lane & 3);

    f4 acc[4];
    #pragma unroll
    for (int c = 0; c < 4; ++c){ const float b = Bv[c*16+eL]; acc[c] = (f4){b,b,b,b}; }

    float xr[8];
    auto loadX = [&](int ch){
        const float4 v0 = *(const float4*)(xg + (size_t)ch*KC);
        const float4 v1 = *(const float4*)(xg + (size_t)ch*KC + 4);
        xr[0]=v0.x; xr[1]=v0.y; xr[2]=v0.z; xr[3]=v0.w;
        xr[4]=v1.x; xr[5]=v1.y; xr[6]=v1.z; xr[7]=v1.w;
    };
    auto gldW = [&](int ch, int buf){
        #pragma unroll
        for (int s = 0; s < 3; ++s)
            gld16(wg + (size_t)s*PLANE + ch*KC, &wsh[buf][s][wv*512]);
    };
    auto writeX = [&](int buf){
        bf8 o0, o1, o2;
        #pragma unroll
        for (int j = 0; j < 8; ++j){
            const float x = xr[j];
            const unsigned short b1 = bf16rn(x);  const float r  = x - bf2f(b1);
            const unsigned short b2 = bf16rn(r);  const float r2 = r - bf2f(b2);
            o0[j] = (short)b1; o1[j] = (short)b2; o2[j] = (short)bf16rn(r2);
        }
        *(bf8*)&xs[buf][0][sr*KC + 8*sj] = o0;
        *(bf8*)&xs[buf][1][sr*KC + 8*sj] = o1;
        *(bf8*)&xs[buf][2][sr*KC + 8*sj] = o2;
    };

    loadX(0); gldW(0, 0); writeX(0);
    __syncthreads();

    for (int ch = 0; ch < NCH; ++ch){
        const int buf = ch & 1;
        if (ch + 1 < NCH){ loadX(ch+1); gldW(ch+1, buf^1); }

        const int rA = (wv*16 + eL)*KC + q*8;
        const bf8 a0 = *(const bf8*)&xs[buf][0][rA];
        const bf8 a1 = *(const bf8*)&xs[buf][1][rA];
        const bf8 a2 = *(const bf8*)&xs[buf][2][rA];
        #pragma unroll
        for (int c = 0; c < 4; ++c){
            const int rB = (c*16 + eL)*KC + q*8;
            const bf8 b0 = *(const bf8*)&wsh[buf][0][rB];
            const bf8 b1 = *(const bf8*)&wsh[buf][1][rB];
            const bf8 b2 = *(const bf8*)&wsh[buf][2][rB];
            // small-terms first: x2w2, x1w3, x3w1, x1w2, x2w1, x1w1
            acc[c] = __builtin_amdgcn_mfma_f32_16x16x32_bf16(a1, b1, acc[c], 0,0,0);
            acc[c] = __builtin_amdgcn_mfma_f32_16x16x32_bf16(a0, b2, acc[c], 0,0,0);
            acc[c] = __builtin_amdgcn_mfma_f32_16x16x32_bf16(a2, b0, acc[c], 0,0,0);
            acc[c] = __builtin_amdgcn_mfma_f32_16x16x32_bf16(a0, b1, acc[c], 0,0,0);
            acc[c] = __builtin_amdgcn_mfma_f32_16x16x32_bf16(a1, b0, acc[c], 0,0,0);
            acc[c] = __builtin_amdgcn_mfma_f32_16x16x32_bf16(a0, b0, acc[c], 0,0,0);
        }
        if (ch + 1 < NCH) writeX(buf^1);
        __syncthreads();
    }

    // ---- epilogue: top-9, gap certification, top-8 + masked softmax ----
    // bf16 C/D layout: token row = 4*(lane>>4) + reg, expert col = c*16 + (lane&15)
    float* probs = out;
    float* idxo  = out + (size_t)NTOK * NEXP;
    int* wl = wsi + 4;

    #pragma unroll
    for (int i = 0; i < 4; ++i){
        const int T = t0 + wv*16 + 4*q + i;
        float v[4];
        #pragma unroll
        for (int c = 0; c < 4; ++c) v[c] = acc[c][i];

        unsigned sel = 0; float m0 = 0.0f, ssum = 0.0f, prevm = 0.0f, mingap = 1e30f;
        int myIdx = 0;
        #pragma unroll
        for (int it = 0; it < 9; ++it){
            float bv = -1e30f; int be = 1 << 30;
            #pragma unroll
            for (int c = 0; c < 4; ++c)
                if (!((sel >> c) & 1) && v[c] > bv){ bv = v[c]; be = c*16 + eL; }
            float gv = bv; int ge = be;
            #pragma unroll
            for (int off = 1; off <= 8; off <<= 1){
                const float ov = __shfl_xor(gv, off, 64);
                const int   oe = __shfl_xor(ge, off, 64);
                if (ov > gv || (ov == gv && oe < ge)){ gv = ov; ge = oe; }
            }
            if (it > 0) mingap = fminf(mingap, prevm - gv);
            prevm = gv;
            if (it < 8){
                if (it == 0) m0 = gv;
                ssum += __expf(gv - m0);
                if ((ge & 15) == eL) sel |= 1u << (ge >> 4);
                if (eL == it) myIdx = ge;
            }
        }
        if (eL == 0 && mingap < DELTA){
            const int pos = atomicAdd(wsi, 1);
            if (pos < WL_CAP) wl[pos] = T;
        }
        const float inv = 1.0f / ssum;
        #pragma unroll
        for (int c = 0; c < 4; ++c){
            const float p = ((sel >> c) & 1) ? __expf(v[c] - m0) * inv : 0.0f;
            probs[(size_t)T * NEXP + c*16 + eL] = p;
        }
        if (eL < TOPK) idxo[(size_t)T * TOPK + eL] = (float)myIdx;
    }
}

// ---- kernel 2: f64 refine of flagged tokens (R1-verified epilogue) ----
__global__ __launch_bounds__(256) void refine(
    const float* __restrict__ X, const float* __restrict__ W,
    const float* __restrict__ Bv, float* __restrict__ out, const int* __restrict__ wsi)
{
    __shared__ double part[4][64];
    const int tid = threadIdx.x, lane = tid & 63, w = tid >> 6;
    int n = wsi[0]; if (n > WL_CAP) n = WL_CAP;
    const int* wl = wsi + 4;
    float* probs = out;
    float* idxo  = out + (size_t)NTOK * NEXP;

    for (int slot = blockIdx.x; slot < n; slot += gridDim.x){
        const int T = wl[slot];
        const float4* xr = (const float4*)(X + (size_t)T*EMB) + w*128;
        const float4* wr = (const float4*)(W + (size_t)lane*EMB) + w*128;
        double a0=0, a1=0, a2=0, a3=0;
        #pragma unroll 4
        for (int i = 0; i < 128; ++i){
            const float4 xv = xr[i], wv4 = wr[i];
            a0 += (double)xv.x * (double)wv4.x;
            a1 += (double)xv.y * (double)wv4.y;
            a2 += (double)xv.z * (double)wv4.z;
            a3 += (double)xv.w * (double)wv4.w;
        }
        part[w][lane] = (a0 + a1) + (a2 + a3);
        __syncthreads();
        if (w == 0){
            const double v = (double)Bv[lane] +
                part[0][lane] + part[1][lane] + part[2][lane] + part[3][lane];
            bool selb = false; int myIdx = 0; double m0 = 0.0; float ssum = 0.0f;
            #pragma unroll
            for (int it = 0; it < TOPK; ++it){
                double x = selb ? -1.0e300 : v;
                double m = x;
                #pragma unroll
                for (int off = 32; off > 0; off >>= 1)
                    m = fmax(m, __shfl_xor(m, off, 64));
                const unsigned long long bm = __ballot(x == m);
                const int src = __ffsll(bm) - 1;
                if (lane == src) selb = true;
                if (lane == it)  myIdx = src;
                if (it == 0)     m0 = m;
                ssum += __expf((float)(m - m0));
            }
            const float p = selb ? __expf((float)(v - m0)) / ssum : 0.0f;
            probs[(size_t)T * NEXP + lane] = p;
            if (lane < TOPK) idxo[(size_t)T * TOPK + lane] = (float)myIdx;
        }
        __syncthreads();
    }
}

extern "C" void kernel_launch(void* const* d_in, const int* in_sizes, int n_in,
                              void* d_out, int out_size, void* d_ws, size_t ws_size,
                              hipStream_t stream) {
    const float* X = (const float*)d_in[0];
    const float* W = (const float*)d_in[1];
    const float* B = (const float*)d_in[2];
    unsigned short* wp = (unsigned short*)((char*)d_ws + WOFF);
    hipMemsetAsync(d_ws, 0, 16, stream);
    wsplit<<<256, 256, 0, stream>>>(W, wp);
    router_bf16<<<NTOK/BT, 256, 0, stream>>>(X, wp, B, (float*)d_out, (int*)d_ws);
    refine<<<512, 256, 0, stream>>>(X, W, B, (float*)d_out, (const int*)d_ws);
}